// Round 10
// baseline (315.677 us; speedup 1.0000x reference)
//
#include <hip/hip_runtime.h>
#include <hip/hip_bf16.h>

// Problem: B=4, S=4096, D=256 single-head causal attention, fp32 in/out.
// ALL tensors in MFMA-fragment order (every attention load = coalesced 1KB):
//  Qf @0:  per 16-row strip s16=global_row>>4 (0..1023): 8KB:
//          frag kk: byte (s16*8+kk)*1024 + lane*16 + e*2 -> Q[row16=lo][d=kk*32+hi*8+e]
//  KV @8MB: per (batch, kv-tile t<64) 64KB block:
//   K [0..32K): frag (nf,kk): byte (nf*8+kk)*1024 + lane*16 + e*2 -> K[s_t=nf*16+lo][d=kk*32+hi*8+e]
//   V [32K..64K): frag (ks,n): byte 32768+(ks*16+n)*1024 + lane*16 + e*2 -> V[s_t=ks*32+hf*8+e][d=n*16+lo]
//  O1/O2/O3 bf16 partials @24/32/40MB; ML fp32 [4][16384][2] @48MB.
// attn_fd2: 2048 one-wave blocks; 32 q-rows/wave (2 strips sharing K/V frags),
// KV split-4; slot=id&15: batch=(slot>>1)&3, chunk=(slot>>3)*2|(slot&1) ->
// XCD x touches 2 quarter-ranges (~2MB) of one batch. 4-way merge.

#define SEQ 4096
#define DIM 256
#define NBATCH 4
#define KVBLK 64
#define KVT_BYTES 65536

#define QB_OFF   0
#define KV_OFF   (8u*1024*1024)
#define O1_OFF   (24u*1024*1024)
#define O2_OFF   (32u*1024*1024)
#define O3_OFF   (40u*1024*1024)
#define ML_OFF   (48u*1024*1024)

typedef __attribute__((ext_vector_type(8))) short bf16x8;
typedef __attribute__((ext_vector_type(4))) float f32x4;
typedef __attribute__((ext_vector_type(4))) unsigned short us4;

static __device__ inline unsigned short f2bf(float f) {
  unsigned int u = __float_as_uint(f);
  u += 0x7FFFu + ((u >> 16) & 1u);
  return (unsigned short)(u >> 16);
}
static __device__ inline float bf2f(unsigned short u) {
  return __uint_as_float(((unsigned int)u) << 16);
}

// ---------------- Kernel 1: QKV projection, fragment-order epilogues ----------------
__global__ __launch_bounds__(256) void qkv_gemm(
    const float* __restrict__ x, const float* __restrict__ Wq,
    const float* __restrict__ Wk, const float* __restrict__ Wv,
    char* __restrict__ qbf, char* __restrict__ kv)
{
  __shared__ unsigned short A_lds[128][40];
  __shared__ unsigned short B_lds[64][40];

  const int tid = threadIdx.x;
  const int lane = tid & 63;
  const int w = tid >> 6;
  const int lo = lane & 15, hi = lane >> 4;
  const int mb = blockIdx.x * 128;
  const int nb = blockIdx.y * 64;
  const int z = blockIdx.z;
  const float* Wm = (z == 0) ? Wq : (z == 1) ? Wk : Wv;

  f32x4 acc[2][4];
#pragma unroll
  for (int mi = 0; mi < 2; mi++)
#pragma unroll
    for (int ni = 0; ni < 4; ni++) acc[mi][ni] = (f32x4){0.f, 0.f, 0.f, 0.f};

  for (int ks = 0; ks < 8; ++ks) {
    const int k0 = ks * 32;
    __syncthreads();
#pragma unroll
    for (int i = 0; i < 4; ++i) {
      int f = tid + i * 256;
      int row = f >> 3, c4 = (f & 7) * 4;
      float4 v = *(const float4*)(x + (size_t)(mb + row) * DIM + k0 + c4);
      us4 bv = { f2bf(v.x), f2bf(v.y), f2bf(v.z), f2bf(v.w) };
      *(us4*)&A_lds[row][c4] = bv;
    }
#pragma unroll
    for (int i = 0; i < 2; ++i) {
      int f = tid + i * 256;
      int row = f >> 3, c4 = (f & 7) * 4;
      float4 v = *(const float4*)(Wm + (size_t)(nb + row) * DIM + k0 + c4);
      us4 bv = { f2bf(v.x), f2bf(v.y), f2bf(v.z), f2bf(v.w) };
      *(us4*)&B_lds[row][c4] = bv;
    }
    __syncthreads();
    bf16x8 a[2], bfr[4];
#pragma unroll
    for (int mi = 0; mi < 2; mi++) a[mi] = *(const bf16x8*)&A_lds[w * 32 + mi * 16 + lo][hi * 8];
#pragma unroll
    for (int ni = 0; ni < 4; ni++) bfr[ni] = *(const bf16x8*)&B_lds[ni * 16 + lo][hi * 8];
#pragma unroll
    for (int mi = 0; mi < 2; mi++)
#pragma unroll
      for (int ni = 0; ni < 4; ni++)
        acc[mi][ni] = __builtin_amdgcn_mfma_f32_16x16x32_bf16(a[mi], bfr[ni], acc[mi][ni], 0, 0, 0);
  }

  if (z == 0) {
    // Q fragment order
#pragma unroll
    for (int mi = 0; mi < 2; mi++) {
      int r0 = mb + w * 32 + mi * 16 + hi * 4;
#pragma unroll
      for (int ni = 0; ni < 4; ni++) {
        int d = nb + ni * 16 + lo;
        int kkq = d >> 5, hiq = (d >> 3) & 3, eq = d & 7;
#pragma unroll
        for (int j = 0; j < 4; j++) {
          int srow = r0 + j;
          int s16 = srow >> 4, loq = srow & 15;
          size_t byte = ((size_t)(s16 * 8 + kkq) << 10) + ((hiq * 16 + loq) << 4) + eq * 2;
          *(unsigned short*)(qbf + byte) = f2bf(acc[mi][ni][j]);
        }
      }
    }
  } else if (z == 1) {
    // K fragment order
#pragma unroll
    for (int mi = 0; mi < 2; mi++) {
      int r0 = mb + w * 32 + mi * 16 + hi * 4;
#pragma unroll
      for (int ni = 0; ni < 4; ni++) {
        int d = nb + ni * 16 + lo;
        int kkk = d >> 5, hik = (d >> 3) & 3, ek = d & 7;
#pragma unroll
        for (int j = 0; j < 4; j++) {
          int srow = r0 + j;
          int bb = srow >> 12, sl = srow & 4095;
          int t = sl >> 6, r = sl & 63;
          int nf = r >> 4, lok = r & 15;
          size_t byte = ((size_t)(bb * 64 + t)) * KVT_BYTES +
                        ((size_t)(nf * 8 + kkk) << 10) + ((hik * 16 + lok) << 4) + ek * 2;
          *(unsigned short*)(kv + byte) = f2bf(acc[mi][ni][j]);
        }
      }
    }
  } else {
    // V fragment order (8B stores)
#pragma unroll
    for (int mi = 0; mi < 2; mi++) {
      int s0 = mb + w * 32 + mi * 16 + hi * 4;
      int bb = s0 >> 12;
      int t = (s0 >> 6) & 63;
      int s_t = s0 & 63;
      int ksI = s_t >> 5;
      int hf = (s_t >> 3) & 3;
      int e0 = s_t & 7;
#pragma unroll
      for (int ni = 0; ni < 4; ni++) {
        int d = nb + ni * 16 + lo;
        int n = d >> 4;
        us4 pv = { f2bf(acc[mi][ni][0]), f2bf(acc[mi][ni][1]),
                   f2bf(acc[mi][ni][2]), f2bf(acc[mi][ni][3]) };
        size_t byte = ((size_t)(bb * 64 + t)) * KVT_BYTES + 32768 +
                      ((size_t)(ksI * 16 + n) << 10) + ((hf * 16 + lo) << 4) + e0 * 2;
        *(us4*)(kv + byte) = pv;
      }
    }
  }
}

// ---------------- Kernel 2a: attn_fd2 (32 rows/wave, KV split-4) ----------------
__global__ __launch_bounds__(64, 2) void attn_fd2(
    const char* __restrict__ qbf, const char* __restrict__ kv,
    float* __restrict__ out, unsigned short* __restrict__ o1,
    unsigned short* __restrict__ o2, unsigned short* __restrict__ o3,
    float* __restrict__ ml)
{
  __shared__ unsigned short P_lds[16][72];

  const int lane = threadIdx.x & 63;
  const int lo = lane & 15, hi = lane >> 4;
  const int id = blockIdx.x;
  const int slot = id & 15;
  const int b = (slot >> 1) & 3;
  const int c = ((slot >> 3) << 1) | (slot & 1);   // 0..3, XCD-bound pair
  const int v = id >> 4;                           // 0..127
  const int qt = (v & 1) ? (127 - (v >> 1)) : (v >> 1);
  const int nt = (qt >> 1) + 1;
  const int t0 = (nt * c) >> 2;
  const int t1 = (nt * (c + 1)) >> 2;
  const int qbase = qt * 32;
  const int rbase = b * SEQ + qbase;
  const float scale = 0.0625f;

  float* mlc = ml + (size_t)c * 16384 * 2;

  if (t0 >= t1) {   // empty chunk
    if (lane < 32) {
      mlc[(size_t)(rbase + lane) * 2 + 0] = -3e38f;
      mlc[(size_t)(rbase + lane) * 2 + 1] = 0.f;
    }
    if (c == 0) {   // zero-fill out rows (chunk0's target)
#pragma unroll
      for (int j = 0; j < 32; j++)
#pragma unroll
        for (int n = 0; n < 4; n++)
          out[(size_t)(rbase + j) * DIM + n * 64 + lane] = 0.f;
    }
    return;
  }

  const char* kv_base = kv + (size_t)b * 64 * KVT_BYTES;
  const char* qp0 = qbf + ((size_t)(b * 256 + qt * 2) << 13) + lane * 16;
  const char* qp1 = qp0 + 8192;

  float m_run[2][4], l_run[2][4];
#pragma unroll
  for (int sp = 0; sp < 2; sp++)
#pragma unroll
    for (int j = 0; j < 4; j++) { m_run[sp][j] = -__builtin_inff(); l_run[sp][j] = 0.f; }
  f32x4 oa0[16], oa1[16];
#pragma unroll
  for (int n = 0; n < 16; n++) { oa0[n] = (f32x4){0.f,0.f,0.f,0.f}; oa1[n] = (f32x4){0.f,0.f,0.f,0.f}; }

  for (int t = t0; t < t1; ++t) {
    const char* tileb = kv_base + (size_t)t * KVT_BYTES;
    const char* kfb = tileb + lane * 16;

    // Q fragments reloaded per iter (hot L2 lines; keeps VGPR under 256)
    bf16x8 qf0[8], qf1[8];
#pragma unroll
    for (int kk = 0; kk < 8; kk++) {
      qf0[kk] = *(const bf16x8*)(qp0 + kk * 1024);
      qf1[kk] = *(const bf16x8*)(qp1 + kk * 1024);
    }

    // S = Q K^T, K fragments shared by both strips
    float s[2][4][4];
#pragma unroll
    for (int nf = 0; nf < 4; nf++) {
      bf16x8 kf[8];
#pragma unroll
      for (int kk = 0; kk < 8; kk++)
        kf[kk] = *(const bf16x8*)(kfb + ((nf * 8 + kk) << 10));
      f32x4 a0 = (f32x4){0.f,0.f,0.f,0.f}, a1 = (f32x4){0.f,0.f,0.f,0.f};
#pragma unroll
      for (int kk = 0; kk < 8; kk++) {
        a0 = __builtin_amdgcn_mfma_f32_16x16x32_bf16(qf0[kk], kf[kk], a0, 0, 0, 0);
        a1 = __builtin_amdgcn_mfma_f32_16x16x32_bf16(qf1[kk], kf[kk], a1, 0, 0, 0);
      }
#pragma unroll
      for (int j = 0; j < 4; j++) { s[0][nf][j] = a0[j] * scale; s[1][nf][j] = a1[j] * scale; }
    }

    // causal mask: only the last tile touches the diagonal
    if (t == nt - 1) {
#pragma unroll
      for (int nf = 0; nf < 4; nf++) {
        int kg = t * KVBLK + nf * 16 + lo;
#pragma unroll
        for (int j = 0; j < 4; j++) {
          int qg0 = qbase + hi * 4 + j;
          if (kg > qg0) s[0][nf][j] = -__builtin_inff();
          if (kg > qg0 + 16) s[1][nf][j] = -__builtin_inff();
        }
      }
    }

    // online softmax (defer-max), both strips
    float vnew[2][4];
#pragma unroll
    for (int sp = 0; sp < 2; sp++)
#pragma unroll
      for (int j = 0; j < 4; j++) {
        float m = fmaxf(fmaxf(s[sp][0][j], s[sp][1][j]), fmaxf(s[sp][2][j], s[sp][3][j]));
        m = fmaxf(m, __shfl_xor(m, 1));
        m = fmaxf(m, __shfl_xor(m, 2));
        m = fmaxf(m, __shfl_xor(m, 4));
        m = fmaxf(m, __shfl_xor(m, 8));
        vnew[sp][j] = m;
      }
    bool grow = false;
#pragma unroll
    for (int sp = 0; sp < 2; sp++)
#pragma unroll
      for (int j = 0; j < 4; j++) grow = grow || (vnew[sp][j] > m_run[sp][j] + 8.f);
    if (__any(grow)) {
#pragma unroll
      for (int j = 0; j < 4; j++) {
        float mn0 = fmaxf(m_run[0][j], vnew[0][j]);
        float mn1 = fmaxf(m_run[1][j], vnew[1][j]);
        float al0 = __expf(m_run[0][j] - mn0);
        float al1 = __expf(m_run[1][j] - mn1);
        m_run[0][j] = mn0; m_run[1][j] = mn1;
        l_run[0][j] *= al0; l_run[1][j] *= al1;
#pragma unroll
        for (int n = 0; n < 16; n++) { oa0[n][j] *= al0; oa1[n][j] *= al1; }
      }
    }
    // exp in place (s becomes P), accumulate l
#pragma unroll
    for (int sp = 0; sp < 2; sp++)
#pragma unroll
      for (int j = 0; j < 4; j++) {
        float sum = 0.f;
#pragma unroll
        for (int nf = 0; nf < 4; nf++) {
          s[sp][nf][j] = __expf(s[sp][nf][j] - m_run[sp][j]);
          sum += s[sp][nf][j];
        }
        sum += __shfl_xor(sum, 1);
        sum += __shfl_xor(sum, 2);
        sum += __shfl_xor(sum, 4);
        sum += __shfl_xor(sum, 8);
        l_run[sp][j] += sum;
      }

    // P -> LDS per strip (wave-local roundtrip)
    bf16x8 pas[2][2];
#pragma unroll
    for (int sp = 0; sp < 2; sp++) {
#pragma unroll
      for (int nf = 0; nf < 4; nf++)
#pragma unroll
        for (int j = 0; j < 4; j++)
          P_lds[hi * 4 + j][nf * 16 + lo] = f2bf(s[sp][nf][j]);
      asm volatile("s_waitcnt lgkmcnt(0)" ::: "memory");
      __builtin_amdgcn_sched_barrier(0);
      pas[sp][0] = *(const bf16x8*)&P_lds[lo][hi * 8];
      pas[sp][1] = *(const bf16x8*)&P_lds[lo][32 + hi * 8];
      asm volatile("s_waitcnt lgkmcnt(0)" ::: "memory");
      __builtin_amdgcn_sched_barrier(0);
    }

    // O += P V; V fragments shared by both strips
    const char* vglob = tileb + 32768 + lane * 16;
#pragma unroll
    for (int g = 0; g < 4; g++) {
      bf16x8 va[4], vb[4];
#pragma unroll
      for (int k = 0; k < 4; k++) {
        int n = g * 4 + k;
        va[k] = *(const bf16x8*)(vglob + (n << 10));
        vb[k] = *(const bf16x8*)(vglob + ((16 + n) << 10));
      }
#pragma unroll
      for (int k = 0; k < 4; k++) {
        int n = g * 4 + k;
        oa0[n] = __builtin_amdgcn_mfma_f32_16x16x32_bf16(pas[0][0], va[k], oa0[n], 0, 0, 0);
        oa0[n] = __builtin_amdgcn_mfma_f32_16x16x32_bf16(pas[0][1], vb[k], oa0[n], 0, 0, 0);
        oa1[n] = __builtin_amdgcn_mfma_f32_16x16x32_bf16(pas[1][0], va[k], oa1[n], 0, 0, 0);
        oa1[n] = __builtin_amdgcn_mfma_f32_16x16x32_bf16(pas[1][1], vb[k], oa1[n], 0, 0, 0);
      }
    }
  }

  // epilogue: c==0 -> fp32 out; else bf16 partial. ml per chunk.
  unsigned short* opc = (c == 1) ? o1 : (c == 2) ? o2 : o3;
#pragma unroll
  for (int sp = 0; sp < 2; sp++) {
#pragma unroll
    for (int j = 0; j < 4; j++) {
      int r = rbase + sp * 16 + hi * 4 + j;
      float l = l_run[sp][j];
      float inv = (l > 0.f) ? 1.f / l : 0.f;
      if (c == 0) {
        float* orow = out + (size_t)r * DIM;
#pragma unroll
        for (int n = 0; n < 16; n++) {
          f32x4 o = sp ? oa1[n] : oa0[n];
          orow[n * 16 + lo] = o[j] * inv;
        }
      } else {
        unsigned short* orow = opc + (size_t)r * DIM;
#pragma unroll
        for (int n = 0; n < 16; n++) {
          f32x4 o = sp ? oa1[n] : oa0[n];
          orow[n * 16 + lo] = f2bf(o[j] * inv);
        }
      }
      if (lo == 0) {
        mlc[(size_t)r * 2 + 0] = m_run[sp][j];
        mlc[(size_t)r * 2 + 1] = l;
      }
    }
  }
}

// ---------------- Kernel 2b: 4-way merge ----------------
__global__ __launch_bounds__(256) void merge4(
    const float* __restrict__ ml,
    const unsigned short* __restrict__ o1, const unsigned short* __restrict__ o2,
    const unsigned short* __restrict__ o3, float* __restrict__ out)
{
  int r = blockIdx.x * 4 + (threadIdx.x >> 6);
  int c4 = (threadIdx.x & 63) * 4;
  float m0 = ml[(size_t)r*2],           l0 = ml[(size_t)r*2+1];
  float m1 = ml[(size_t)(16384+r)*2],   l1 = ml[(size_t)(16384+r)*2+1];
  float m2 = ml[(size_t)(32768+r)*2],   l2 = ml[(size_t)(32768+r)*2+1];
  float m3 = ml[(size_t)(49152+r)*2],   l3 = ml[(size_t)(49152+r)*2+1];
  float M = fmaxf(fmaxf(m0, m1), fmaxf(m2, m3));
  float w0 = l0 * __expf(m0 - M);
  float w1 = l1 * __expf(m1 - M);
  float w2 = l2 * __expf(m2 - M);
  float w3 = l3 * __expf(m3 - M);
  float inv = 1.f / (w0 + w1 + w2 + w3);
  float4 o0 = *(const float4*)(out + (size_t)r * DIM + c4);
  us4 a  = *(const us4*)(o1 + (size_t)r * DIM + c4);
  us4 bq = *(const us4*)(o2 + (size_t)r * DIM + c4);
  us4 cq = *(const us4*)(o3 + (size_t)r * DIM + c4);
  float4 res;
  res.x = (w0*o0.x + w1*bf2f(a.x) + w2*bf2f(bq.x) + w3*bf2f(cq.x)) * inv;
  res.y = (w0*o0.y + w1*bf2f(a.y) + w2*bf2f(bq.y) + w3*bf2f(cq.y)) * inv;
  res.z = (w0*o0.z + w1*bf2f(a.z) + w2*bf2f(bq.z) + w3*bf2f(cq.z)) * inv;
  res.w = (w0*o0.w + w1*bf2f(a.w) + w2*bf2f(bq.w) + w3*bf2f(cq.w)) * inv;
  *(float4*)(out + (size_t)r * DIM + c4) = res;
}

extern "C" void kernel_launch(void* const* d_in, const int* in_sizes, int n_in,
                              void* d_out, int out_size, void* d_ws, size_t ws_size,
                              hipStream_t stream) {
  const float* x  = (const float*)d_in[0];
  const float* Wq = (const float*)d_in[1];
  const float* Wk = (const float*)d_in[2];
  const float* Wv = (const float*)d_in[3];
  char* ws = (char*)d_ws;
  char* qbf = ws + QB_OFF;
  char* kv  = ws + KV_OFF;
  unsigned short* o1 = (unsigned short*)(ws + O1_OFF);
  unsigned short* o2 = (unsigned short*)(ws + O2_OFF);
  unsigned short* o3 = (unsigned short*)(ws + O3_OFF);
  float* ml = (float*)(ws + ML_OFF);
  float* out = (float*)d_out;

  qkv_gemm<<<dim3(128, 4, 3), 256, 0, stream>>>(x, Wq, Wk, Wv, qbf, kv);
  attn_fd2<<<dim3(2048), 64, 0, stream>>>(qbf, kv, out, o1, o2, o3, ml);
  merge4<<<dim3(4096), 256, 0, stream>>>(ml, o1, o2, o3, out);
}

// Round 11
// 139.135 us; speedup vs baseline: 2.2688x; 2.2688x over previous
//
#include <hip/hip_runtime.h>
#include <hip/hip_bf16.h>

// Problem: B=4, S=4096, D=256 single-head causal attention, fp32 in/out.
// ALL tensors in MFMA-fragment order (every attention load = coalesced 1KB):
//  Qf @0:  per 16-row strip s16=global_row>>4 (0..1023): 8KB:
//          frag kk: byte (s16*8+kk)*1024 + lane*16 + e*2 -> Q[row16=lo][d=kk*32+hi*8+e]
//  KV @8MB: per (batch, kv-tile t<64) 64KB block:
//   K [0..32K): frag (nf,kk): byte (nf*8+kk)*1024 + lane*16 + e*2 -> K[s_t=nf*16+lo][d=kk*32+hi*8+e]
//   V [32K..64K): frag (ks,n): byte 32768+(ks*16+n)*1024 + lane*16 + e*2 -> V[s_t=ks*32+hf*8+e][d=n*16+lo]
//  O1/O2/O3 bf16 partials @24/32/40MB; ML fp32 [4][16384][2] @48MB.
// attn_pair: 2048 one-wave blocks; block (p,c) does {chunk c of qt=p} then
// {chunk 3-c of qt=255-p}: nt(p)+nt(255-p)=65 -> every block ~16-17 iters
// (balanced per-CU by construction). Q pinned in regs per task (R10 lesson:
// never reload Q per iter). XCD binding: batch=(id&7)>>1, chunk parity=id&1.

#define SEQ 4096
#define DIM 256
#define NBATCH 4
#define KVBLK 64
#define KVT_BYTES 65536

#define QB_OFF   0
#define KV_OFF   (8u*1024*1024)
#define O1_OFF   (24u*1024*1024)
#define O2_OFF   (32u*1024*1024)
#define O3_OFF   (40u*1024*1024)
#define ML_OFF   (48u*1024*1024)

typedef __attribute__((ext_vector_type(8))) short bf16x8;
typedef __attribute__((ext_vector_type(4))) float f32x4;
typedef __attribute__((ext_vector_type(4))) unsigned short us4;

static __device__ inline unsigned short f2bf(float f) {
  unsigned int u = __float_as_uint(f);
  u += 0x7FFFu + ((u >> 16) & 1u);
  return (unsigned short)(u >> 16);
}
static __device__ inline float bf2f(unsigned short u) {
  return __uint_as_float(((unsigned int)u) << 16);
}

// ---------------- Kernel 1: QKV projection, fragment-order epilogues ----------------
__global__ __launch_bounds__(256) void qkv_gemm(
    const float* __restrict__ x, const float* __restrict__ Wq,
    const float* __restrict__ Wk, const float* __restrict__ Wv,
    char* __restrict__ qbf, char* __restrict__ kv)
{
  __shared__ unsigned short A_lds[128][40];
  __shared__ unsigned short B_lds[64][40];

  const int tid = threadIdx.x;
  const int lane = tid & 63;
  const int w = tid >> 6;
  const int lo = lane & 15, hi = lane >> 4;
  const int mb = blockIdx.x * 128;
  const int nb = blockIdx.y * 64;
  const int z = blockIdx.z;
  const float* Wm = (z == 0) ? Wq : (z == 1) ? Wk : Wv;

  f32x4 acc[2][4];
#pragma unroll
  for (int mi = 0; mi < 2; mi++)
#pragma unroll
    for (int ni = 0; ni < 4; ni++) acc[mi][ni] = (f32x4){0.f, 0.f, 0.f, 0.f};

  for (int ks = 0; ks < 8; ++ks) {
    const int k0 = ks * 32;
    __syncthreads();
#pragma unroll
    for (int i = 0; i < 4; ++i) {
      int f = tid + i * 256;
      int row = f >> 3, c4 = (f & 7) * 4;
      float4 v = *(const float4*)(x + (size_t)(mb + row) * DIM + k0 + c4);
      us4 bv = { f2bf(v.x), f2bf(v.y), f2bf(v.z), f2bf(v.w) };
      *(us4*)&A_lds[row][c4] = bv;
    }
#pragma unroll
    for (int i = 0; i < 2; ++i) {
      int f = tid + i * 256;
      int row = f >> 3, c4 = (f & 7) * 4;
      float4 v = *(const float4*)(Wm + (size_t)(nb + row) * DIM + k0 + c4);
      us4 bv = { f2bf(v.x), f2bf(v.y), f2bf(v.z), f2bf(v.w) };
      *(us4*)&B_lds[row][c4] = bv;
    }
    __syncthreads();
    bf16x8 a[2], bfr[4];
#pragma unroll
    for (int mi = 0; mi < 2; mi++) a[mi] = *(const bf16x8*)&A_lds[w * 32 + mi * 16 + lo][hi * 8];
#pragma unroll
    for (int ni = 0; ni < 4; ni++) bfr[ni] = *(const bf16x8*)&B_lds[ni * 16 + lo][hi * 8];
#pragma unroll
    for (int mi = 0; mi < 2; mi++)
#pragma unroll
      for (int ni = 0; ni < 4; ni++)
        acc[mi][ni] = __builtin_amdgcn_mfma_f32_16x16x32_bf16(a[mi], bfr[ni], acc[mi][ni], 0, 0, 0);
  }

  if (z == 0) {
    // Q fragment order
#pragma unroll
    for (int mi = 0; mi < 2; mi++) {
      int r0 = mb + w * 32 + mi * 16 + hi * 4;
#pragma unroll
      for (int ni = 0; ni < 4; ni++) {
        int d = nb + ni * 16 + lo;
        int kkq = d >> 5, hiq = (d >> 3) & 3, eq = d & 7;
#pragma unroll
        for (int j = 0; j < 4; j++) {
          int srow = r0 + j;
          int s16 = srow >> 4, loq = srow & 15;
          size_t byte = ((size_t)(s16 * 8 + kkq) << 10) + ((hiq * 16 + loq) << 4) + eq * 2;
          *(unsigned short*)(qbf + byte) = f2bf(acc[mi][ni][j]);
        }
      }
    }
  } else if (z == 1) {
    // K fragment order
#pragma unroll
    for (int mi = 0; mi < 2; mi++) {
      int r0 = mb + w * 32 + mi * 16 + hi * 4;
#pragma unroll
      for (int ni = 0; ni < 4; ni++) {
        int d = nb + ni * 16 + lo;
        int kkk = d >> 5, hik = (d >> 3) & 3, ek = d & 7;
#pragma unroll
        for (int j = 0; j < 4; j++) {
          int srow = r0 + j;
          int bb = srow >> 12, sl = srow & 4095;
          int t = sl >> 6, r = sl & 63;
          int nf = r >> 4, lok = r & 15;
          size_t byte = ((size_t)(bb * 64 + t)) * KVT_BYTES +
                        ((size_t)(nf * 8 + kkk) << 10) + ((hik * 16 + lok) << 4) + ek * 2;
          *(unsigned short*)(kv + byte) = f2bf(acc[mi][ni][j]);
        }
      }
    }
  } else {
    // V fragment order (8B stores)
#pragma unroll
    for (int mi = 0; mi < 2; mi++) {
      int s0 = mb + w * 32 + mi * 16 + hi * 4;
      int bb = s0 >> 12;
      int t = (s0 >> 6) & 63;
      int s_t = s0 & 63;
      int ksI = s_t >> 5;
      int hf = (s_t >> 3) & 3;
      int e0 = s_t & 7;
#pragma unroll
      for (int ni = 0; ni < 4; ni++) {
        int d = nb + ni * 16 + lo;
        int n = d >> 4;
        us4 pv = { f2bf(acc[mi][ni][0]), f2bf(acc[mi][ni][1]),
                   f2bf(acc[mi][ni][2]), f2bf(acc[mi][ni][3]) };
        size_t byte = ((size_t)(bb * 64 + t)) * KVT_BYTES + 32768 +
                      ((size_t)(ksI * 16 + n) << 10) + ((hf * 16 + lo) << 4) + e0 * 2;
        *(us4*)(kv + byte) = pv;
      }
    }
  }
}

// ---------------- Kernel 2a: attn_pair (complement-paired, split-4) ----------------
// 2048 blocks x 64 thr. id&7 = x: batch=x>>1, chunk-lsb=x&1. v=id>>3 (0..255):
// p=v&127, chunk-msb=v>>7. Tasks: (qt=p, c) then (qt=255-p, 3-c).
__global__ __launch_bounds__(64, 2) void attn_pair(
    const char* __restrict__ qbf, const char* __restrict__ kv,
    float* __restrict__ out, unsigned short* __restrict__ o1,
    unsigned short* __restrict__ o2, unsigned short* __restrict__ o3,
    float* __restrict__ ml)
{
  __shared__ unsigned short P_lds[16][72];

  const int lane = threadIdx.x & 63;
  const int lo = lane & 15, hi = lane >> 4;
  const int id = blockIdx.x;
  const int x = id & 7;
  const int b = x >> 1;
  const int v = id >> 3;
  const int p = v & 127;
  const int cbase = ((v >> 7) << 1) | (x & 1);   // 0..3
  const float scale = 0.0625f;

  const char* kv_base = kv + (size_t)b * 64 * KVT_BYTES;

  for (int task = 0; task < 2; ++task) {
    const int qt = task ? (255 - p) : p;
    const int cc = task ? (3 - cbase) : cbase;
    const int nt = (qt >> 2) + 1;
    const int t0 = (nt * cc) >> 2;
    const int t1 = (nt * (cc + 1)) >> 2;
    const int rbase = b * SEQ + qt * 16;
    float* mlc = ml + (size_t)cc * 16384 * 2;

    if (t0 >= t1) {   // empty chunk (only possible for nt<4, i.e. qt<12)
      if (lane < 16) {
        mlc[(size_t)(rbase + lane) * 2 + 0] = -3e38f;
        mlc[(size_t)(rbase + lane) * 2 + 1] = 0.f;
      }
      if (cc == 0) {
#pragma unroll
        for (int j = 0; j < 16; j++)
#pragma unroll
          for (int n = 0; n < 4; n++)
            out[(size_t)(rbase + j) * DIM + n * 64 + lane] = 0.f;
      }
      continue;
    }

    // Q fragments pinned in registers for this task (8 coalesced 1KB loads)
    bf16x8 qf[8];
    {
      const char* qp = qbf + ((size_t)(b * 256 + qt) << 13) + lane * 16;
#pragma unroll
      for (int kk = 0; kk < 8; kk++)
        qf[kk] = *(const bf16x8*)(qp + kk * 1024);
    }

    float m_run[4], l_run[4];
#pragma unroll
    for (int j = 0; j < 4; j++) { m_run[j] = -__builtin_inff(); l_run[j] = 0.f; }
    f32x4 o_acc[16];
#pragma unroll
    for (int n = 0; n < 16; n++) o_acc[n] = (f32x4){0.f, 0.f, 0.f, 0.f};

    for (int t = t0; t < t1; ++t) {
      const char* tileb = kv_base + (size_t)t * KVT_BYTES;
      const char* kfb = tileb + lane * 16;

      // S = Q K^T; K frags coalesced, double-buffered across nf groups
      bf16x8 kf[2][8];
#pragma unroll
      for (int kk = 0; kk < 8; kk++)
        kf[0][kk] = *(const bf16x8*)(kfb + kk * 1024);

      f32x4 sf[4];
#pragma unroll
      for (int nf = 0; nf < 4; nf++) {
        if (nf < 3) {
#pragma unroll
          for (int kk = 0; kk < 8; kk++)
            kf[(nf + 1) & 1][kk] = *(const bf16x8*)(kfb + ((nf + 1) * 8 + kk) * 1024);
        }
        f32x4 a = (f32x4){0.f, 0.f, 0.f, 0.f};
#pragma unroll
        for (int kk = 0; kk < 8; kk++)
          a = __builtin_amdgcn_mfma_f32_16x16x32_bf16(qf[kk], kf[nf & 1][kk], a, 0, 0, 0);
        sf[nf] = a;
      }

      const bool diag = (t == nt - 1);
      float s[4][4];
#pragma unroll
      for (int nf = 0; nf < 4; nf++)
#pragma unroll
        for (int j = 0; j < 4; j++) {
          float vv = sf[nf][j] * scale;
          if (diag) {
            int qg = qt * 16 + hi * 4 + j;
            int kg = t * KVBLK + nf * 16 + lo;
            if (kg > qg) vv = -__builtin_inff();
          }
          s[nf][j] = vv;
        }

      // online softmax with defer-max
      float vnew[4];
#pragma unroll
      for (int j = 0; j < 4; j++) {
        float m = fmaxf(fmaxf(s[0][j], s[1][j]), fmaxf(s[2][j], s[3][j]));
        m = fmaxf(m, __shfl_xor(m, 1));
        m = fmaxf(m, __shfl_xor(m, 2));
        m = fmaxf(m, __shfl_xor(m, 4));
        m = fmaxf(m, __shfl_xor(m, 8));
        vnew[j] = m;
      }
      bool grow = false;
#pragma unroll
      for (int j = 0; j < 4; j++) grow = grow || (vnew[j] > m_run[j] + 8.f);
      if (__any(grow)) {
#pragma unroll
        for (int j = 0; j < 4; j++) {
          float mn = fmaxf(m_run[j], vnew[j]);
          float alpha = __expf(m_run[j] - mn);
          m_run[j] = mn;
          l_run[j] *= alpha;
#pragma unroll
          for (int n = 0; n < 16; n++) o_acc[n][j] *= alpha;
        }
      }
      float pr[4][4];
#pragma unroll
      for (int j = 0; j < 4; j++) {
        float sum = 0.f;
#pragma unroll
        for (int nf = 0; nf < 4; nf++) {
          pr[nf][j] = __expf(s[nf][j] - m_run[j]);
          sum += pr[nf][j];
        }
        sum += __shfl_xor(sum, 1);
        sum += __shfl_xor(sum, 2);
        sum += __shfl_xor(sum, 4);
        sum += __shfl_xor(sum, 8);
        l_run[j] += sum;
      }

      // P -> LDS roundtrip (wave-local)
#pragma unroll
      for (int nf = 0; nf < 4; nf++)
#pragma unroll
        for (int j = 0; j < 4; j++)
          P_lds[hi * 4 + j][nf * 16 + lo] = f2bf(pr[nf][j]);
      asm volatile("s_waitcnt lgkmcnt(0)" ::: "memory");
      __builtin_amdgcn_sched_barrier(0);
      bf16x8 pa0 = *(const bf16x8*)&P_lds[lo][hi * 8];
      bf16x8 pa1 = *(const bf16x8*)&P_lds[lo][32 + hi * 8];
      asm volatile("s_waitcnt lgkmcnt(0)" ::: "memory");
      __builtin_amdgcn_sched_barrier(0);

      // O += P V; V frags coalesced 1KB
      const char* vglob = tileb + 32768 + lane * 16;
#pragma unroll
      for (int g = 0; g < 4; g++) {
        bf16x8 va[4], vb[4];
#pragma unroll
        for (int k = 0; k < 4; k++) {
          int n = g * 4 + k;
          va[k] = *(const bf16x8*)(vglob + (n << 10));
          vb[k] = *(const bf16x8*)(vglob + ((16 + n) << 10));
        }
#pragma unroll
        for (int k = 0; k < 4; k++) {
          o_acc[g * 4 + k] = __builtin_amdgcn_mfma_f32_16x16x32_bf16(pa0, va[k], o_acc[g * 4 + k], 0, 0, 0);
          o_acc[g * 4 + k] = __builtin_amdgcn_mfma_f32_16x16x32_bf16(pa1, vb[k], o_acc[g * 4 + k], 0, 0, 0);
        }
      }
    }

    // epilogue: cc==0 -> fp32 out; else bf16 partial. ml per chunk.
    unsigned short* opc = (cc == 1) ? o1 : (cc == 2) ? o2 : o3;
#pragma unroll
    for (int j = 0; j < 4; j++) {
      int r = rbase + hi * 4 + j;
      float l = l_run[j];
      float inv = (l > 0.f) ? 1.f / l : 0.f;
      if (cc == 0) {
        float* orow = out + (size_t)r * DIM;
#pragma unroll
        for (int n = 0; n < 16; n++)
          orow[n * 16 + lo] = o_acc[n][j] * inv;
      } else {
        unsigned short* orow = opc + (size_t)r * DIM;
#pragma unroll
        for (int n = 0; n < 16; n++)
          orow[n * 16 + lo] = f2bf(o_acc[n][j] * inv);
      }
      if (lo == 0) {
        mlc[(size_t)r * 2 + 0] = m_run[j];
        mlc[(size_t)r * 2 + 1] = l;
      }
    }
  }
}

// ---------------- Kernel 2b: 4-way merge ----------------
__global__ __launch_bounds__(256) void merge4(
    const float* __restrict__ ml,
    const unsigned short* __restrict__ o1, const unsigned short* __restrict__ o2,
    const unsigned short* __restrict__ o3, float* __restrict__ out)
{
  int r = blockIdx.x * 4 + (threadIdx.x >> 6);
  int c4 = (threadIdx.x & 63) * 4;
  float m0 = ml[(size_t)r*2],           l0 = ml[(size_t)r*2+1];
  float m1 = ml[(size_t)(16384+r)*2],   l1 = ml[(size_t)(16384+r)*2+1];
  float m2 = ml[(size_t)(32768+r)*2],   l2 = ml[(size_t)(32768+r)*2+1];
  float m3 = ml[(size_t)(49152+r)*2],   l3 = ml[(size_t)(49152+r)*2+1];
  float M = fmaxf(fmaxf(m0, m1), fmaxf(m2, m3));
  float w0 = l0 * __expf(m0 - M);
  float w1 = l1 * __expf(m1 - M);
  float w2 = l2 * __expf(m2 - M);
  float w3 = l3 * __expf(m3 - M);
  float inv = 1.f / (w0 + w1 + w2 + w3);
  float4 o0 = *(const float4*)(out + (size_t)r * DIM + c4);
  us4 a  = *(const us4*)(o1 + (size_t)r * DIM + c4);
  us4 bq = *(const us4*)(o2 + (size_t)r * DIM + c4);
  us4 cq = *(const us4*)(o3 + (size_t)r * DIM + c4);
  float4 res;
  res.x = (w0*o0.x + w1*bf2f(a.x) + w2*bf2f(bq.x) + w3*bf2f(cq.x)) * inv;
  res.y = (w0*o0.y + w1*bf2f(a.y) + w2*bf2f(bq.y) + w3*bf2f(cq.y)) * inv;
  res.z = (w0*o0.z + w1*bf2f(a.z) + w2*bf2f(bq.z) + w3*bf2f(cq.z)) * inv;
  res.w = (w0*o0.w + w1*bf2f(a.w) + w2*bf2f(bq.w) + w3*bf2f(cq.w)) * inv;
  *(float4*)(out + (size_t)r * DIM + c4) = res;
}

extern "C" void kernel_launch(void* const* d_in, const int* in_sizes, int n_in,
                              void* d_out, int out_size, void* d_ws, size_t ws_size,
                              hipStream_t stream) {
  const float* x  = (const float*)d_in[0];
  const float* Wq = (const float*)d_in[1];
  const float* Wk = (const float*)d_in[2];
  const float* Wv = (const float*)d_in[3];
  char* ws = (char*)d_ws;
  char* qbf = ws + QB_OFF;
  char* kv  = ws + KV_OFF;
  unsigned short* o1 = (unsigned short*)(ws + O1_OFF);
  unsigned short* o2 = (unsigned short*)(ws + O2_OFF);
  unsigned short* o3 = (unsigned short*)(ws + O3_OFF);
  float* ml = (float*)(ws + ML_OFF);
  float* out = (float*)d_out;

  qkv_gemm<<<dim3(128, 4, 3), 256, 0, stream>>>(x, Wq, Wk, Wv, qbf, kv);
  attn_pair<<<dim3(2048), 64, 0, stream>>>(qbf, kv, out, o1, o2, o3, ml);
  merge4<<<dim3(4096), 256, 0, stream>>>(ml, o1, o2, o3, out);
}

// Round 12
// 117.630 us; speedup vs baseline: 2.6837x; 1.1828x over previous
//
#include <hip/hip_runtime.h>
#include <hip/hip_bf16.h>

// Problem: B=4, S=4096, D=256 single-head causal attention, fp32 in/out.
// ALL tensors in MFMA-fragment order (fragment = contiguous 1KB, lane*16):
//  Qf @0:  strip s16=row>>4: 8KB; frag kk at (s16*8+kk)*1024
//  KV @8MB: per (batch, kv-tile t<64) 64KB: K frags [0..32K) (nf*8+kk)*1024;
//           V frags [32K..64K) (ks*16+n)*1024
//  O1/O2/O3 bf16 partials @24/32/40MB; ML fp32 [4][16384][2] @48MB.
// attn_fa: 256 blocks x 512 thr (8 waves, 1 block/CU). Block stages each 64KB
// KV tile into LDS once (linear global_load_lds, dbuf, counted vmcnt); 8 waves
// (128 q-rows) share it -> 8x arithmetic intensity vs R11. Complement-paired
// runs (u,31-u) x chunks (c,3-c): ~16.5 tiles/block, balanced by construction.

#define SEQ 4096
#define DIM 256
#define NBATCH 4
#define KVBLK 64
#define KVT_BYTES 65536

#define QB_OFF   0
#define KV_OFF   (8u*1024*1024)
#define O1_OFF   (24u*1024*1024)
#define O2_OFF   (32u*1024*1024)
#define O3_OFF   (40u*1024*1024)
#define ML_OFF   (48u*1024*1024)

typedef __attribute__((ext_vector_type(8))) short bf16x8;
typedef __attribute__((ext_vector_type(4))) float f32x4;
typedef __attribute__((ext_vector_type(4))) unsigned short us4;

static __device__ inline unsigned short f2bf(float f) {
  unsigned int u = __float_as_uint(f);
  u += 0x7FFFu + ((u >> 16) & 1u);
  return (unsigned short)(u >> 16);
}
static __device__ inline float bf2f(unsigned short u) {
  return __uint_as_float(((unsigned int)u) << 16);
}

// ---------------- Kernel 1: QKV projection, fragment-order epilogues ----------------
__global__ __launch_bounds__(256) void qkv_gemm(
    const float* __restrict__ x, const float* __restrict__ Wq,
    const float* __restrict__ Wk, const float* __restrict__ Wv,
    char* __restrict__ qbf, char* __restrict__ kv)
{
  __shared__ unsigned short A_lds[128][40];
  __shared__ unsigned short B_lds[64][40];

  const int tid = threadIdx.x;
  const int lane = tid & 63;
  const int w = tid >> 6;
  const int lo = lane & 15, hi = lane >> 4;
  const int mb = blockIdx.x * 128;
  const int nb = blockIdx.y * 64;
  const int z = blockIdx.z;
  const float* Wm = (z == 0) ? Wq : (z == 1) ? Wk : Wv;

  f32x4 acc[2][4];
#pragma unroll
  for (int mi = 0; mi < 2; mi++)
#pragma unroll
    for (int ni = 0; ni < 4; ni++) acc[mi][ni] = (f32x4){0.f, 0.f, 0.f, 0.f};

  for (int ks = 0; ks < 8; ++ks) {
    const int k0 = ks * 32;
    __syncthreads();
#pragma unroll
    for (int i = 0; i < 4; ++i) {
      int f = tid + i * 256;
      int row = f >> 3, c4 = (f & 7) * 4;
      float4 v = *(const float4*)(x + (size_t)(mb + row) * DIM + k0 + c4);
      us4 bv = { f2bf(v.x), f2bf(v.y), f2bf(v.z), f2bf(v.w) };
      *(us4*)&A_lds[row][c4] = bv;
    }
#pragma unroll
    for (int i = 0; i < 2; ++i) {
      int f = tid + i * 256;
      int row = f >> 3, c4 = (f & 7) * 4;
      float4 v = *(const float4*)(Wm + (size_t)(nb + row) * DIM + k0 + c4);
      us4 bv = { f2bf(v.x), f2bf(v.y), f2bf(v.z), f2bf(v.w) };
      *(us4*)&B_lds[row][c4] = bv;
    }
    __syncthreads();
    bf16x8 a[2], bfr[4];
#pragma unroll
    for (int mi = 0; mi < 2; mi++) a[mi] = *(const bf16x8*)&A_lds[w * 32 + mi * 16 + lo][hi * 8];
#pragma unroll
    for (int ni = 0; ni < 4; ni++) bfr[ni] = *(const bf16x8*)&B_lds[ni * 16 + lo][hi * 8];
#pragma unroll
    for (int mi = 0; mi < 2; mi++)
#pragma unroll
      for (int ni = 0; ni < 4; ni++)
        acc[mi][ni] = __builtin_amdgcn_mfma_f32_16x16x32_bf16(a[mi], bfr[ni], acc[mi][ni], 0, 0, 0);
  }

  if (z == 0) {
    // Q fragment order
#pragma unroll
    for (int mi = 0; mi < 2; mi++) {
      int r0 = mb + w * 32 + mi * 16 + hi * 4;
#pragma unroll
      for (int ni = 0; ni < 4; ni++) {
        int d = nb + ni * 16 + lo;
        int kkq = d >> 5, hiq = (d >> 3) & 3, eq = d & 7;
#pragma unroll
        for (int j = 0; j < 4; j++) {
          int srow = r0 + j;
          int s16 = srow >> 4, loq = srow & 15;
          size_t byte = ((size_t)(s16 * 8 + kkq) << 10) + ((hiq * 16 + loq) << 4) + eq * 2;
          *(unsigned short*)(qbf + byte) = f2bf(acc[mi][ni][j]);
        }
      }
    }
  } else if (z == 1) {
    // K fragment order
#pragma unroll
    for (int mi = 0; mi < 2; mi++) {
      int r0 = mb + w * 32 + mi * 16 + hi * 4;
#pragma unroll
      for (int ni = 0; ni < 4; ni++) {
        int d = nb + ni * 16 + lo;
        int kkk = d >> 5, hik = (d >> 3) & 3, ek = d & 7;
#pragma unroll
        for (int j = 0; j < 4; j++) {
          int srow = r0 + j;
          int bb = srow >> 12, sl = srow & 4095;
          int t = sl >> 6, r = sl & 63;
          int nf = r >> 4, lok = r & 15;
          size_t byte = ((size_t)(bb * 64 + t)) * KVT_BYTES +
                        ((size_t)(nf * 8 + kkk) << 10) + ((hik * 16 + lok) << 4) + ek * 2;
          *(unsigned short*)(kv + byte) = f2bf(acc[mi][ni][j]);
        }
      }
    }
  } else {
    // V fragment order (8B stores)
#pragma unroll
    for (int mi = 0; mi < 2; mi++) {
      int s0 = mb + w * 32 + mi * 16 + hi * 4;
      int bb = s0 >> 12;
      int t = (s0 >> 6) & 63;
      int s_t = s0 & 63;
      int ksI = s_t >> 5;
      int hf = (s_t >> 3) & 3;
      int e0 = s_t & 7;
#pragma unroll
      for (int ni = 0; ni < 4; ni++) {
        int d = nb + ni * 16 + lo;
        int n = d >> 4;
        us4 pv = { f2bf(acc[mi][ni][0]), f2bf(acc[mi][ni][1]),
                   f2bf(acc[mi][ni][2]), f2bf(acc[mi][ni][3]) };
        size_t byte = ((size_t)(bb * 64 + t)) * KVT_BYTES + 32768 +
                      ((size_t)(ksI * 16 + n) << 10) + ((hf * 16 + lo) << 4) + e0 * 2;
        *(us4*)(kv + byte) = pv;
      }
    }
  }
}

// ---------------- Kernel 2a: attn_fa (8-wave LDS-shared KV, paired runs) ----------------
// 256 blocks x 512 thr. id&7=x: batch=x>>1, chunk-lsb=x&1. v=id>>3 (0..31):
// p=v&15, chunk-msb=v>>4. Tasks: (run p, c) then (run 31-p, 3-c).
// Run u = 128 q-rows (8 waves x 16); nt(u)=2u+2; chunk cc -> tiles [nt*cc/4, nt*(cc+1)/4).
__global__ __launch_bounds__(512, 1) void attn_fa(
    const char* __restrict__ qbf, const char* __restrict__ kv,
    float* __restrict__ out, unsigned short* __restrict__ o1,
    unsigned short* __restrict__ o2, unsigned short* __restrict__ o3,
    float* __restrict__ ml)
{
  __shared__ char KV_lds[2][KVT_BYTES];        // 128KB double buffer (linear frags)
  __shared__ unsigned short P_lds[8][16][72];

  const int tid = threadIdx.x;
  const int lane = tid & 63;
  const int w = tid >> 6;
  const int lo = lane & 15, hi = lane >> 4;
  const int id = blockIdx.x;
  const int x = id & 7;
  const int b = x >> 1;
  const int v = id >> 3;
  const int p = v & 15;
  const int cbase = ((v >> 4) << 1) | (x & 1);   // 0..3
  const float scale = 0.0625f;

  const char* kv_base = kv + (size_t)b * 64 * KVT_BYTES;

  auto stageKV = [&](int t, int buf) {
    const char* src = kv_base + (size_t)t * KVT_BYTES + tid * 16;
    char* dst = &KV_lds[buf][0] + tid * 16;
#pragma unroll
    for (int i = 0; i < 8; ++i) {
      __builtin_amdgcn_global_load_lds(
          (const __attribute__((address_space(1))) void*)(src + i * 8192),
          (__attribute__((address_space(3))) void*)(dst + i * 8192),
          16, 0, 0);
    }
  };

  for (int task = 0; task < 2; ++task) {
    const int u = task ? (15 - p) + 16 : p;      // run: p then 31-p
    const int cc = task ? (3 - cbase) : cbase;
    const int nt = 2 * u + 2;
    const int t0 = (nt * cc) >> 2;
    const int t1 = (nt * (cc + 1)) >> 2;
    const int qrow0 = u * 128 + w * 16;          // wave's first q row (in batch)
    const int rbase = b * SEQ + qrow0;
    float* mlc = ml + (size_t)cc * 16384 * 2;

    if (t0 >= t1) {   // empty chunk (u=0: chunks 0 and 2)
      if (lane < 16) {
        mlc[(size_t)(rbase + lane) * 2 + 0] = -3e38f;
        mlc[(size_t)(rbase + lane) * 2 + 1] = 0.f;
      }
      if (cc == 0) {
#pragma unroll
        for (int j = 0; j < 16; j++)
#pragma unroll
          for (int n = 0; n < 4; n++)
            out[(size_t)(rbase + j) * DIM + n * 64 + lane] = 0.f;
      }
      continue;
    }

    // Q fragments pinned (issued BEFORE stages so vmcnt(8) retires them too)
    bf16x8 qf[8];
    {
      const char* qp = qbf + ((size_t)(b * 256 + u * 8 + w) << 13) + lane * 16;
#pragma unroll
      for (int kk = 0; kk < 8; kk++)
        qf[kk] = *(const bf16x8*)(qp + kk * 1024);
    }

    stageKV(t0, 0);
    if (t0 + 1 < t1) stageKV(t0 + 1, 1);

    float m_run[4], l_run[4];
#pragma unroll
    for (int j = 0; j < 4; j++) { m_run[j] = -3e38f; l_run[j] = 0.f; }
    f32x4 o_acc[16];
#pragma unroll
    for (int n = 0; n < 16; n++) o_acc[n] = (f32x4){0.f, 0.f, 0.f, 0.f};

    for (int t = t0; t < t1; ++t) {
      const int cur = (t - t0) & 1;

      // stage(t) complete; stage(t+1)'s 8 loads/thread may stay in flight
      if (t + 1 < t1) {
        asm volatile("s_waitcnt vmcnt(8)" ::: "memory");
      } else {
        asm volatile("s_waitcnt vmcnt(0)" ::: "memory");
      }
      __builtin_amdgcn_sched_barrier(0);
      __builtin_amdgcn_s_barrier();   // all waves: buffer cur fully staged

      const char* kt = &KV_lds[cur][0] + lane * 16;

      // S = Q K^T (K frags from LDS, conflict-free ds_read_b128)
      f32x4 sf[4];
#pragma unroll
      for (int nf = 0; nf < 4; nf++) {
        bf16x8 kf[8];
#pragma unroll
        for (int kk = 0; kk < 8; kk++)
          kf[kk] = *(const bf16x8*)(kt + ((nf * 8 + kk) << 10));
        f32x4 a = (f32x4){0.f, 0.f, 0.f, 0.f};
#pragma unroll
        for (int kk = 0; kk < 8; kk++)
          a = __builtin_amdgcn_mfma_f32_16x16x32_bf16(qf[kk], kf[kk], a, 0, 0, 0);
        sf[nf] = a;
      }

      // scale + causal mask (mask whenever tile can exceed this wave's rows)
      const bool needmask = (t * KVBLK + KVBLK - 1) > qrow0;
      float s[4][4];
#pragma unroll
      for (int nf = 0; nf < 4; nf++)
#pragma unroll
        for (int j = 0; j < 4; j++) {
          float vv = sf[nf][j] * scale;
          if (needmask) {
            int qg = qrow0 + hi * 4 + j;
            int kg = t * KVBLK + nf * 16 + lo;
            if (kg > qg) vv = -__builtin_inff();
          }
          s[nf][j] = vv;
        }

      // online softmax with defer-max (init -3e38 so all-masked rows stay clean)
      float vnew[4];
#pragma unroll
      for (int j = 0; j < 4; j++) {
        float m = fmaxf(fmaxf(s[0][j], s[1][j]), fmaxf(s[2][j], s[3][j]));
        m = fmaxf(m, __shfl_xor(m, 1));
        m = fmaxf(m, __shfl_xor(m, 2));
        m = fmaxf(m, __shfl_xor(m, 4));
        m = fmaxf(m, __shfl_xor(m, 8));
        vnew[j] = m;
      }
      bool grow = false;
#pragma unroll
      for (int j = 0; j < 4; j++) grow = grow || (vnew[j] > m_run[j] + 8.f);
      if (__any(grow)) {
#pragma unroll
        for (int j = 0; j < 4; j++) {
          float mn = fmaxf(m_run[j], vnew[j]);
          float alpha = __expf(m_run[j] - mn);
          m_run[j] = mn;
          l_run[j] *= alpha;
#pragma unroll
          for (int n = 0; n < 16; n++) o_acc[n][j] *= alpha;
        }
      }
      float pr[4][4];
#pragma unroll
      for (int j = 0; j < 4; j++) {
        float sum = 0.f;
#pragma unroll
        for (int nf = 0; nf < 4; nf++) {
          pr[nf][j] = __expf(s[nf][j] - m_run[j]);
          sum += pr[nf][j];
        }
        sum += __shfl_xor(sum, 1);
        sum += __shfl_xor(sum, 2);
        sum += __shfl_xor(sum, 4);
        sum += __shfl_xor(sum, 8);
        l_run[j] += sum;
      }

      // P -> per-wave LDS roundtrip
#pragma unroll
      for (int nf = 0; nf < 4; nf++)
#pragma unroll
        for (int j = 0; j < 4; j++)
          P_lds[w][hi * 4 + j][nf * 16 + lo] = f2bf(pr[nf][j]);
      asm volatile("s_waitcnt lgkmcnt(0)" ::: "memory");
      __builtin_amdgcn_sched_barrier(0);
      bf16x8 pa0 = *(const bf16x8*)&P_lds[w][lo][hi * 8];
      bf16x8 pa1 = *(const bf16x8*)&P_lds[w][lo][32 + hi * 8];
      asm volatile("s_waitcnt lgkmcnt(0)" ::: "memory");
      __builtin_amdgcn_sched_barrier(0);

      // O += P V (V frags from LDS)
      const char* vt = &KV_lds[cur][32768] + lane * 16;
#pragma unroll
      for (int g = 0; g < 4; g++) {
        bf16x8 va[4], vb[4];
#pragma unroll
        for (int k = 0; k < 4; k++) {
          int n = g * 4 + k;
          va[k] = *(const bf16x8*)(vt + (n << 10));
          vb[k] = *(const bf16x8*)(vt + ((16 + n) << 10));
        }
#pragma unroll
        for (int k = 0; k < 4; k++) {
          o_acc[g * 4 + k] = __builtin_amdgcn_mfma_f32_16x16x32_bf16(pa0, va[k], o_acc[g * 4 + k], 0, 0, 0);
          o_acc[g * 4 + k] = __builtin_amdgcn_mfma_f32_16x16x32_bf16(pa1, vb[k], o_acc[g * 4 + k], 0, 0, 0);
        }
      }

      __builtin_amdgcn_sched_barrier(0);
      __builtin_amdgcn_s_barrier();   // all waves done reading buffer cur
      if (t + 2 < t1) stageKV(t + 2, cur);
    }

    // epilogue: cc==0 -> fp32 out; else bf16 partial. ml per chunk.
    unsigned short* opc = (cc == 1) ? o1 : (cc == 2) ? o2 : o3;
#pragma unroll
    for (int j = 0; j < 4; j++) {
      int r = rbase + hi * 4 + j;
      float l = l_run[j];
      float inv = (l > 0.f) ? 1.f / l : 0.f;
      if (cc == 0) {
        float* orow = out + (size_t)r * DIM;
#pragma unroll
        for (int n = 0; n < 16; n++)
          orow[n * 16 + lo] = o_acc[n][j] * inv;
      } else {
        unsigned short* orow = opc + (size_t)r * DIM;
#pragma unroll
        for (int n = 0; n < 16; n++)
          orow[n * 16 + lo] = f2bf(o_acc[n][j] * inv);
      }
      if (lo == 0) {
        mlc[(size_t)r * 2 + 0] = m_run[j];
        mlc[(size_t)r * 2 + 1] = l;
      }
    }
  }
}

// ---------------- Kernel 2b: 4-way merge ----------------
__global__ __launch_bounds__(256) void merge4(
    const float* __restrict__ ml,
    const unsigned short* __restrict__ o1, const unsigned short* __restrict__ o2,
    const unsigned short* __restrict__ o3, float* __restrict__ out)
{
  int r = blockIdx.x * 4 + (threadIdx.x >> 6);
  int c4 = (threadIdx.x & 63) * 4;
  float m0 = ml[(size_t)r*2],           l0 = ml[(size_t)r*2+1];
  float m1 = ml[(size_t)(16384+r)*2],   l1 = ml[(size_t)(16384+r)*2+1];
  float m2 = ml[(size_t)(32768+r)*2],   l2 = ml[(size_t)(32768+r)*2+1];
  float m3 = ml[(size_t)(49152+r)*2],   l3 = ml[(size_t)(49152+r)*2+1];
  float M = fmaxf(fmaxf(m0, m1), fmaxf(m2, m3));
  float w0 = l0 * __expf(m0 - M);
  float w1 = l1 * __expf(m1 - M);
  float w2 = l2 * __expf(m2 - M);
  float w3 = l3 * __expf(m3 - M);
  float inv = 1.f / (w0 + w1 + w2 + w3);
  float4 o0 = *(const float4*)(out + (size_t)r * DIM + c4);
  us4 a  = *(const us4*)(o1 + (size_t)r * DIM + c4);
  us4 bq = *(const us4*)(o2 + (size_t)r * DIM + c4);
  us4 cq = *(const us4*)(o3 + (size_t)r * DIM + c4);
  float4 res;
  res.x = (w0*o0.x + w1*bf2f(a.x) + w2*bf2f(bq.x) + w3*bf2f(cq.x)) * inv;
  res.y = (w0*o0.y + w1*bf2f(a.y) + w2*bf2f(bq.y) + w3*bf2f(cq.y)) * inv;
  res.z = (w0*o0.z + w1*bf2f(a.z) + w2*bf2f(bq.z) + w3*bf2f(cq.z)) * inv;
  res.w = (w0*o0.w + w1*bf2f(a.w) + w2*bf2f(bq.w) + w3*bf2f(cq.w)) * inv;
  *(float4*)(out + (size_t)r * DIM + c4) = res;
}

extern "C" void kernel_launch(void* const* d_in, const int* in_sizes, int n_in,
                              void* d_out, int out_size, void* d_ws, size_t ws_size,
                              hipStream_t stream) {
  const float* x  = (const float*)d_in[0];
  const float* Wq = (const float*)d_in[1];
  const float* Wk = (const float*)d_in[2];
  const float* Wv = (const float*)d_in[3];
  char* ws = (char*)d_ws;
  char* qbf = ws + QB_OFF;
  char* kv  = ws + KV_OFF;
  unsigned short* o1 = (unsigned short*)(ws + O1_OFF);
  unsigned short* o2 = (unsigned short*)(ws + O2_OFF);
  unsigned short* o3 = (unsigned short*)(ws + O3_OFF);
  float* ml = (float*)(ws + ML_OFF);
  float* out = (float*)d_out;

  qkv_gemm<<<dim3(128, 4, 3), 256, 0, stream>>>(x, Wq, Wk, Wv, qbf, kv);
  attn_fa<<<dim3(256), 512, 0, stream>>>(qbf, kv, out, o1, o2, o3, ml);
  merge4<<<dim3(4096), 256, 0, stream>>>(ml, o1, o2, o3, out);
}